// Round 1
// 3141.681 us; speedup vs baseline: 1.5376x; 1.5376x over previous
//
#include <hip/hip_runtime.h>

// ---------------------------------------------------------------------------
// VQ-VAE forward: H=256, D=64, K=512, STEPS=4, B=16, T=32768, KS=3 (fp32)
// Decoder transposed convs converted to split-bf16 (hi/lo) MFMA GEMMs.
// ---------------------------------------------------------------------------

typedef __attribute__((ext_vector_type(8))) __bf16 bf16x8;
typedef __attribute__((ext_vector_type(16))) float f32x16;
typedef __attribute__((ext_vector_type(8))) unsigned short u16x8;

__device__ __forceinline__ int swz(int u) { return u + ((u >> 5) << 2); }

__device__ __forceinline__ unsigned short f2bf(float x) {
  unsigned u = __float_as_uint(x);
  return (unsigned short)((u + 0x7FFFu + ((u >> 16) & 1u)) >> 16);
}
__device__ __forceinline__ float bf2f(unsigned short h) {
  return __uint_as_float(((unsigned)h) << 16);
}
__device__ __forceinline__ bf16x8 ldwf(const unsigned short* p) {
  return __builtin_bit_cast(bf16x8, *(const u16x8*)p);
}
__device__ __forceinline__ f32x16 MFMA(bf16x8 a, bf16x8 b, f32x16 c) {
  return __builtin_amdgcn_mfma_f32_32x32x16_bf16(a, b, c, 0, 0, 0);
}

// ---------------- enc0: Ci=1, stride 2, k=3, ReLU ----------------
__global__ __launch_bounds__(256)
void enc0_kernel(const float* __restrict__ x, const float* __restrict__ w,
                 const float* __restrict__ bias, float* __restrict__ y, int T) {
  const int To = T >> 1;
  const int b = blockIdx.z, co = blockIdx.y;
  const int t = (blockIdx.x * 256 + threadIdx.x) * 4;
  const float* xb = x + (size_t)b * T;
  const float w0 = w[co * 3 + 0], w1 = w[co * 3 + 1], w2 = w[co * 3 + 2];
  const float bv = bias[co];
  float v[4];
#pragma unroll
  for (int j = 0; j < 4; j++) {
    const int tt = t + j;
    const int ti = 2 * tt - 1;
    const float a = (ti >= 0) ? xb[ti] : 0.f;
    v[j] = fmaxf(fmaf(w0, a, fmaf(w1, xb[ti + 1], fmaf(w2, xb[ti + 2], bv))), 0.f);
  }
  *(float4*)(y + ((size_t)b * 256 + co) * To + t) = make_float4(v[0], v[1], v[2], v[3]);
}

// ---------------- big conv: Ci=256, Co=256, stride 2, k=3 ----------------
template <bool RELU>
__global__ __launch_bounds__(256)
void conv_big_s2(const float* __restrict__ x, const float* __restrict__ w,
                 const float* __restrict__ bias, float* __restrict__ y, int Ti) {
  constexpr int CI = 256;
  const int To = Ti >> 1;
  const int b = blockIdx.z;
  const int co0 = blockIdx.y * 128;
  const int t0 = blockIdx.x * 128;
  const int tid = threadIdx.x;
  const int tx = tid & 15, ty = tid >> 4;

  __shared__ float sW[16][3][132];
  __shared__ float sXe[16][144];
  __shared__ float sXo[16][148];

  const float* xb = x + (size_t)b * CI * Ti;
  float acc[8][8];
#pragma unroll
  for (int i = 0; i < 8; i++)
#pragma unroll
    for (int j = 0; j < 8; j++) acc[i][j] = 0.f;

  const int be = swz(8 * tx);
  const int be8 = swz(8 * tx + 8);

  for (int cc = 0; cc < CI; cc += 16) {
    for (int i = tid; i < 1536; i += 256) {
      const int co = i / 12, q = i - co * 12;
      const float4 v = *(const float4*)(w + (size_t)(co0 + co) * (CI * 3) + cc * 3 + q * 4);
      const float vv[4] = {v.x, v.y, v.z, v.w};
#pragma unroll
      for (int j = 0; j < 4; j++) {
        const int mm = q * 4 + j;
        const int ci = mm / 3, k = mm - ci * 3;
        sW[ci][k][co] = vv[j];
      }
    }
    for (int i = tid; i < 16 * 128; i += 256) {
      const int ci = i >> 7, u = i & 127;
      sXe[ci][swz(u)] = xb[(size_t)(cc + ci) * Ti + 2 * (t0 + u)];
    }
    for (int i = tid; i < 16 * 129; i += 256) {
      const int ci = i / 129, u = i - ci * 129;
      const int t = 2 * (t0 + u) - 1;
      sXo[ci][swz(u)] = (t >= 0) ? xb[(size_t)(cc + ci) * Ti + t] : 0.f;
    }
    __syncthreads();

#pragma unroll 2
    for (int ci = 0; ci < 16; ci++) {
      float xe[8], xo[9], wv[8];
#pragma unroll
      for (int j = 0; j < 8; j++) xe[j] = sXe[ci][be + j];
#pragma unroll
      for (int j = 0; j < 8; j++) xo[j] = sXo[ci][be + j];
      xo[8] = sXo[ci][be8];
#pragma unroll
      for (int i = 0; i < 8; i++) wv[i] = sW[ci][1][8 * ty + i];
#pragma unroll
      for (int i = 0; i < 8; i++)
#pragma unroll
        for (int j = 0; j < 8; j++) acc[i][j] = fmaf(wv[i], xe[j], acc[i][j]);
#pragma unroll
      for (int i = 0; i < 8; i++) wv[i] = sW[ci][0][8 * ty + i];
#pragma unroll
      for (int i = 0; i < 8; i++)
#pragma unroll
        for (int j = 0; j < 8; j++) acc[i][j] = fmaf(wv[i], xo[j], acc[i][j]);
#pragma unroll
      for (int i = 0; i < 8; i++) wv[i] = sW[ci][2][8 * ty + i];
#pragma unroll
      for (int i = 0; i < 8; i++)
#pragma unroll
        for (int j = 0; j < 8; j++) acc[i][j] = fmaf(wv[i], xo[j + 1], acc[i][j]);
    }
    __syncthreads();
  }

#pragma unroll
  for (int i = 0; i < 8; i++) {
    const int co = co0 + 8 * ty + i;
    const float bv = bias[co];
    float* yp = y + ((size_t)b * 256 + co) * To + t0 + 8 * tx;
    float v[8];
#pragma unroll
    for (int j = 0; j < 8; j++) {
      const float s = acc[i][j] + bv;
      v[j] = RELU ? fmaxf(s, 0.f) : s;
    }
    ((float4*)yp)[0] = make_float4(v[0], v[1], v[2], v[3]);
    ((float4*)yp)[1] = make_float4(v[4], v[5], v[6], v[7]);
  }
}

// ---------------- stride-1 conv: tile 64co x 128t, 4x8 per thread ----------
template <int CI, bool RELU>
__global__ __launch_bounds__(256)
void conv_s1(const float* __restrict__ x, const float* __restrict__ w,
             const float* __restrict__ bias, float* __restrict__ y,
             int Ti, int Co) {
  const int b = blockIdx.z;
  const int co0 = blockIdx.y * 64;
  const int t0 = blockIdx.x * 128;
  const int tid = threadIdx.x;
  const int tx = tid & 15, ty = tid >> 4;

  __shared__ float sW[16][3][68];
  __shared__ float sX[16][148];

  const float* xb = x + (size_t)b * CI * Ti;
  float acc[4][8];
#pragma unroll
  for (int i = 0; i < 4; i++)
#pragma unroll
    for (int j = 0; j < 8; j++) acc[i][j] = 0.f;

  const int be = swz(8 * tx);
  const int be8 = swz(8 * tx + 8);

  for (int cc = 0; cc < CI; cc += 16) {
    for (int i = tid; i < 768; i += 256) {
      const int co = i / 12, q = i - co * 12;
      const float4 v = *(const float4*)(w + (size_t)(co0 + co) * (CI * 3) + cc * 3 + q * 4);
      const float vv[4] = {v.x, v.y, v.z, v.w};
#pragma unroll
      for (int j = 0; j < 4; j++) {
        const int mm = q * 4 + j;
        const int ci = mm / 3, k = mm - ci * 3;
        sW[ci][k][co] = vv[j];
      }
    }
    for (int i = tid; i < 16 * 130; i += 256) {
      const int ci = i / 130, u = i - ci * 130;
      const int t = t0 + u - 1;
      sX[ci][swz(u)] = (t >= 0 && t < Ti) ? xb[(size_t)(cc + ci) * Ti + t] : 0.f;
    }
    __syncthreads();

#pragma unroll 2
    for (int ci = 0; ci < 16; ci++) {
      float xw[10], wv[4];
#pragma unroll
      for (int j = 0; j < 8; j++) xw[j] = sX[ci][be + j];
      xw[8] = sX[ci][be8];
      xw[9] = sX[ci][be8 + 1];
#pragma unroll
      for (int k = 0; k < 3; k++) {
#pragma unroll
        for (int i = 0; i < 4; i++) wv[i] = sW[ci][k][4 * ty + i];
#pragma unroll
        for (int i = 0; i < 4; i++)
#pragma unroll
          for (int j = 0; j < 8; j++) acc[i][j] = fmaf(wv[i], xw[j + k], acc[i][j]);
      }
    }
    __syncthreads();
  }

#pragma unroll
  for (int i = 0; i < 4; i++) {
    const int co = co0 + 4 * ty + i;
    const float bv = bias[co];
    float* yp = y + ((size_t)b * Co + co) * Ti + t0 + 8 * tx;
    float v[8];
#pragma unroll
    for (int j = 0; j < 8; j++) {
      const float s = acc[i][j] + bv;
      v[j] = RELU ? fmaxf(s, 0.f) : s;
    }
    ((float4*)yp)[0] = make_float4(v[0], v[1], v[2], v[3]);
    ((float4*)yp)[1] = make_float4(v[4], v[5], v[6], v[7]);
  }
}

// ---------------- weight pack: [co][ci][k] fp32 -> [k][hi/lo][co][ci] bf16 --
__global__ __launch_bounds__(256)
void pack_w_kernel(const float* __restrict__ w, unsigned short* __restrict__ wp) {
  const int co = blockIdx.x, ci = threadIdx.x;
#pragma unroll
  for (int k = 0; k < 3; k++) {
    const float v = w[(size_t)co * 768 + ci * 3 + k];
    const unsigned short h = f2bf(v);
    const float lo = v - bf2f(h);
    wp[(size_t)(k * 2 + 0) * 65536 + co * 256 + ci] = h;
    wp[(size_t)(k * 2 + 1) * 65536 + co * 256 + ci] = f2bf(lo);
  }
}

// ---------------- transposed conv s=2 via split-bf16 MFMA ------------------
// ye[co,u] = sum_ci W1[co,ci]*x[ci,u]
// yo[co,u] = sum_ci W0[co,ci]*x[ci,u] + W2[co,ci]*x[ci,u+1]
// block: 512 thr / 8 waves, tile 256co x 128u (=256 out t).
// waves: wrow=w>>1 (4 rows of 64 co, mt=2 x 32), wcol=w&1 (2 cols of 64 u, nt=2 x 32).
// X staged per 64-ci quarter into LDS [t 129][ci 64] bf16 hi/lo planes,
// 16B-chunk XOR swizzle (chunk ^ (t&7)) -> conflict-free ds_read_b128.
// W read directly from packed global (L2-resident).
template <bool RELU>
__global__ __launch_bounds__(512, 2)
void convt_mfma(const float* __restrict__ x, const unsigned short* __restrict__ wp,
                const float* __restrict__ bias, float* __restrict__ y, int Tin) {
  const int To = Tin * 2;
  const int b = blockIdx.z;
  const int u0 = blockIdx.x * 128;
  const int tid = threadIdx.x;
  const int lane = tid & 63;
  const int wv = tid >> 6;
  const int wrow = wv >> 1;
  const int wcol = wv & 1;
  const int l31 = lane & 31, lhi = lane >> 5;

  __shared__ __align__(16) unsigned short ldsH[129 * 64];
  __shared__ __align__(16) unsigned short ldsL[129 * 64];

  const float* xb = x + (size_t)b * 256 * Tin;

  f32x16 ae[2][2], ao[2][2];
#pragma unroll
  for (int m = 0; m < 2; m++)
#pragma unroll
    for (int n = 0; n < 2; n++)
#pragma unroll
      for (int r = 0; r < 16; r++) { ae[m][n][r] = 0.f; ao[m][n][r] = 0.f; }

  float pv[2][8];   // preloaded X for next quarter: [t-half][ci]
  float pedge;      // t=128 edge value (wave 0 only)

  auto preload = [&](int qq) {
    const int ci0 = qq * 64;
    const int cil = wv * 8;  // this wave's 8 ci rows within quarter
#pragma unroll
    for (int th = 0; th < 2; th++) {
      const int t = th * 64 + lane;
      const float* xp = xb + (size_t)(ci0 + cil) * Tin + u0 + t;
#pragma unroll
      for (int c = 0; c < 8; c++) pv[th][c] = xp[(size_t)c * Tin];
    }
    if (tid < 64) {
      pedge = (u0 + 128 < Tin) ? xb[(size_t)(ci0 + tid) * Tin + u0 + 128] : 0.f;
    }
  };

  auto stagewrite = [&]() {
#pragma unroll
    for (int th = 0; th < 2; th++) {
      const int t = th * 64 + lane;
      u16x8 hv, lv;
#pragma unroll
      for (int c = 0; c < 8; c++) {
        const float v = pv[th][c];
        const unsigned short hh = f2bf(v);
        hv[c] = hh;
        lv[c] = f2bf(v - bf2f(hh));
      }
      const int byte = t * 128 + ((wv ^ (t & 7)) << 4);
      *(u16x8*)((char*)ldsH + byte) = hv;
      *(u16x8*)((char*)ldsL + byte) = lv;
    }
    if (tid < 64) {
      const float v = pedge;
      const unsigned short hh = f2bf(v);
      const int byte = 128 * 128 + ((tid >> 3) << 4) + ((tid & 7) << 1);
      *(unsigned short*)((char*)ldsH + byte) = hh;
      *(unsigned short*)((char*)ldsL + byte) = f2bf(v - bf2f(hh));
    }
  };

  preload(0);

  for (int qq = 0; qq < 4; ++qq) {
    if (qq) __syncthreads();   // previous quarter's readers done
    stagewrite();
    __syncthreads();
    if (qq < 3) preload(qq + 1);  // overlap HBM latency with compute below

#pragma unroll
    for (int kc = 0; kc < 4; ++kc) {
      // B fragments: [n][shift] hi/lo
      bf16x8 bxh[2][2], bxl[2][2];
#pragma unroll
      for (int n = 0; n < 2; n++) {
#pragma unroll
        for (int s = 0; s < 2; s++) {
          const int tl = wcol * 64 + n * 32 + l31 + s;
          const int byte = tl * 128 + (((kc * 2 + lhi) ^ (tl & 7)) << 4);
          bxh[n][s] = __builtin_bit_cast(bf16x8, *(const u16x8*)((const char*)ldsH + byte));
          bxl[n][s] = __builtin_bit_cast(bf16x8, *(const u16x8*)((const char*)ldsL + byte));
        }
      }
      const int cig = qq * 64 + kc * 16 + (lhi << 3);
#pragma unroll
      for (int m = 0; m < 2; m++) {
        const int corow = wrow * 64 + m * 32 + l31;
        const unsigned short* wpb = wp + (size_t)corow * 256 + cig;
        const bf16x8 a0h = ldwf(wpb + 0 * 65536);
        const bf16x8 a0l = ldwf(wpb + 1 * 65536);
        const bf16x8 a1h = ldwf(wpb + 2 * 65536);
        const bf16x8 a1l = ldwf(wpb + 3 * 65536);
        const bf16x8 a2h = ldwf(wpb + 4 * 65536);
        const bf16x8 a2l = ldwf(wpb + 5 * 65536);
#pragma unroll
        for (int n = 0; n < 2; n++) {
          ae[m][n] = MFMA(a1h, bxh[n][0], ae[m][n]);
          ae[m][n] = MFMA(a1h, bxl[n][0], ae[m][n]);
          ae[m][n] = MFMA(a1l, bxh[n][0], ae[m][n]);
          ao[m][n] = MFMA(a0h, bxh[n][0], ao[m][n]);
          ao[m][n] = MFMA(a0h, bxl[n][0], ao[m][n]);
          ao[m][n] = MFMA(a0l, bxh[n][0], ao[m][n]);
          ao[m][n] = MFMA(a2h, bxh[n][1], ao[m][n]);
          ao[m][n] = MFMA(a2h, bxl[n][1], ao[m][n]);
          ao[m][n] = MFMA(a2l, bxh[n][1], ao[m][n]);
        }
      }
    }
  }

  // epilogue: C/D layout 32x32: col=lane&31, row=(r&3)+8*(r>>2)+4*(lane>>5)
  float* yb = y + (size_t)b * 256 * To;
#pragma unroll
  for (int m = 0; m < 2; m++) {
#pragma unroll
    for (int n = 0; n < 2; n++) {
      const int u = u0 + wcol * 64 + n * 32 + l31;
#pragma unroll
      for (int r = 0; r < 16; r++) {
        const int row = (r & 3) + ((r >> 2) << 3) + (lhi << 2);
        const int co = wrow * 64 + m * 32 + row;
        const float bv = bias[co];
        float e = ae[m][n][r] + bv;
        float o = ao[m][n][r] + bv;
        if (RELU) { e = fmaxf(e, 0.f); o = fmaxf(o, 0.f); }
        *(float2*)(yb + ((size_t)co * To + 2 * u)) = make_float2(e, o);
      }
    }
  }
}

// ---------------- codebook norms ----------------
__global__ __launch_bounds__(256)
void cnorm_kernel(const float* __restrict__ cb, float* __restrict__ cn) {
  const int c = blockIdx.x * 256 + threadIdx.x;
  const float* p = cb + (size_t)c * 64;
  float s = 0.f;
#pragma unroll
  for (int d = 0; d < 64; d++) s = fmaf(p[d], p[d], s);
  cn[c] = s;
}

// ---------------- VQ nearest-code + gather ----------------
__global__ __launch_bounds__(256)
void vq_kernel(const float* __restrict__ z, const float* __restrict__ cb,
               const float* __restrict__ cn, float* __restrict__ st) {
  const int Tl = 2048;
  const int b = blockIdx.y, t0 = blockIdx.x * 64;
  const int tid = threadIdx.x, tt = tid & 63, g = tid >> 6;

  __shared__ float zs[64][65];
  for (int i = tid; i < 4096; i += 256) {
    const int d = i >> 6, t = i & 63;
    zs[d][t] = z[((size_t)b * 64 + d) * Tl + t0 + t];
  }
  __syncthreads();

  float zr[64];
#pragma unroll
  for (int d = 0; d < 64; d++) zr[d] = zs[d][tt];

  float best = 3.4e38f;
  int bidx = 0;
  const float* cp = cb + (size_t)g * 128 * 64;
  for (int c = 0; c < 128; c++) {
    const float4* c4 = (const float4*)(cp + (size_t)c * 64);
    float acc = 0.f;
#pragma unroll
    for (int q = 0; q < 16; q++) {
      const float4 v = c4[q];
      acc = fmaf(zr[4 * q + 0], v.x, acc);
      acc = fmaf(zr[4 * q + 1], v.y, acc);
      acc = fmaf(zr[4 * q + 2], v.z, acc);
      acc = fmaf(zr[4 * q + 3], v.w, acc);
    }
    const float dist = cn[g * 128 + c] - 2.f * acc;
    if (dist < best) { best = dist; bidx = g * 128 + c; }
  }

  __shared__ float bd[4][64];
  __shared__ int bi[4][64];
  __shared__ int widx[64];
  bd[g][tt] = best;
  bi[g][tt] = bidx;
  __syncthreads();
  if (tid < 64) {
    float bb = bd[0][tid];
    int ii = bi[0][tid];
#pragma unroll
    for (int g2 = 1; g2 < 4; g2++) {
      if (bd[g2][tid] < bb) { bb = bd[g2][tid]; ii = bi[g2][tid]; }
    }
    widx[tid] = ii;
  }
  __syncthreads();
  for (int i = tid; i < 4096; i += 256) {
    const int d = i >> 6, t = i & 63;
    st[((size_t)b * 64 + d) * Tl + t0 + t] = cb[(size_t)widx[t] * 64 + d];
  }
}

// ---------------------------------------------------------------------------
extern "C" void kernel_launch(void* const* d_in, const int* in_sizes, int n_in,
                              void* d_out, int out_size, void* d_ws, size_t ws_size,
                              hipStream_t stream) {
  const float* inputs    = (const float*)d_in[0];
  const float* enc_w_in  = (const float*)d_in[1];
  const float* enc_b_in  = (const float*)d_in[2];
  const float* enc_ws_p  = (const float*)d_in[3];
  const float* enc_bs_p  = (const float*)d_in[4];
  const float* enc_w_out = (const float*)d_in[5];
  const float* enc_b_out = (const float*)d_in[6];
  const float* codebook  = (const float*)d_in[7];
  const float* dec_w_in  = (const float*)d_in[8];
  const float* dec_b_in  = (const float*)d_in[9];
  const float* dec_ws_p  = (const float*)d_in[10];
  const float* dec_bs_p  = (const float*)d_in[11];
  const float* dec_w_out = (const float*)d_in[12];
  const float* dec_b_out = (const float*)d_in[13];
  float* out = (float*)d_out;
  float* ws = (float*)d_ws;

  const int T = 32768, H = 256;
  const size_t PB = 8126464;  // fp32 elements of workspace per batch

  int Bg = 16;
  while (Bg > 1 && (PB * (size_t)Bg * 4 + 2048) > ws_size) Bg >>= 1;
  const int groups = 16 / Bg;

  float* cnorm = ws + PB * (size_t)Bg;
  float* A0 = ws;                              // enc0 out [Bg,256,16384]
  float* A1 = ws + (size_t)4194304 * Bg;       // enc1 out [Bg,256,8192]
  float* A2 = ws + (size_t)6291456 * Bg;       // enc2 out [Bg,256,4096]
  float* A3 = ws + (size_t)7340032 * Bg;       // enc3 out [Bg,256,2048]
  float* Z  = ws + (size_t)7864320 * Bg;       // z  [Bg,64,2048]
  float* ST = ws + (size_t)7995392 * Bg;       // st [Bg,64,2048]
  float* B0 = ws;                              // dec_in out [Bg,256,2048]
  float* B1 = ws + (size_t)524288 * Bg;        // [Bg,256,4096]
  float* B2 = ws + (size_t)1572864 * Bg;       // [Bg,256,8192]
  float* B3 = ws + (size_t)3670016 * Bg;       // [Bg,256,16384]

  // packed weights (bf16 hi/lo, 393216 ushorts = 786 KB) live in the Z region,
  // which is dead once vq+dec_in have run; repacked per layer, per group.
  unsigned short* wpack = (unsigned short*)(ws + (size_t)7864320 * Bg);

  cnorm_kernel<<<dim3(2), dim3(256), 0, stream>>>(codebook, cnorm);

  for (int gr = 0; gr < groups; gr++) {
    const float* xg = inputs + (size_t)gr * Bg * T;
    float* outg = out + (size_t)gr * Bg * H * T;

    enc0_kernel<<<dim3(16, 256, Bg), 256, 0, stream>>>(xg, enc_w_in, enc_b_in, A0, T);
    conv_big_s2<true><<<dim3(64, 2, Bg), 256, 0, stream>>>(A0, enc_ws_p + 0 * 196608, enc_bs_p + 0 * H, A1, 16384);
    conv_big_s2<true><<<dim3(32, 2, Bg), 256, 0, stream>>>(A1, enc_ws_p + 1 * 196608, enc_bs_p + 1 * H, A2, 8192);
    conv_big_s2<true><<<dim3(16, 2, Bg), 256, 0, stream>>>(A2, enc_ws_p + 2 * 196608, enc_bs_p + 2 * H, A3, 4096);
    conv_s1<256, false><<<dim3(16, 1, Bg), 256, 0, stream>>>(A3, enc_w_out, enc_b_out, Z, 2048, 64);
    vq_kernel<<<dim3(32, Bg), 256, 0, stream>>>(Z, codebook, cnorm, ST);
    conv_s1<64, true><<<dim3(16, 4, Bg), 256, 0, stream>>>(ST, dec_w_in, dec_b_in, B0, 2048, 256);

    pack_w_kernel<<<dim3(256), dim3(256), 0, stream>>>(dec_ws_p + 0 * 196608, wpack);
    convt_mfma<true><<<dim3(16, 1, Bg), 512, 0, stream>>>(B0, wpack, dec_bs_p + 0 * H, B1, 2048);
    pack_w_kernel<<<dim3(256), dim3(256), 0, stream>>>(dec_ws_p + 1 * 196608, wpack);
    convt_mfma<true><<<dim3(32, 1, Bg), 512, 0, stream>>>(B1, wpack, dec_bs_p + 1 * H, B2, 4096);
    pack_w_kernel<<<dim3(256), dim3(256), 0, stream>>>(dec_ws_p + 2 * 196608, wpack);
    convt_mfma<true><<<dim3(64, 1, Bg), 512, 0, stream>>>(B2, wpack, dec_bs_p + 2 * H, B3, 8192);
    pack_w_kernel<<<dim3(256), dim3(256), 0, stream>>>(dec_w_out, wpack);
    convt_mfma<false><<<dim3(128, 1, Bg), 512, 0, stream>>>(B3, wpack, dec_b_out, outg, 16384);
  }
}